// Round 7
// baseline (238.725 us; speedup 1.0000x reference)
//
#include <hip/hip_runtime.h>

#define NN 50000
#define NE 800000
#define NG 64
#define DPART (NN / 8)

typedef float f32x4 __attribute__((ext_vector_type(4)));
typedef short bf16x8 __attribute__((ext_vector_type(8)));
typedef unsigned short ushort_t;

__device__ __forceinline__ ushort_t f2bf(float x) {
  unsigned int u = __float_as_uint(x);
  u = (u + 0x7FFFu + ((u >> 16) & 1u)) >> 16;
  return (ushort_t)u;
}
__device__ __forceinline__ unsigned int bfpack2(float lo, float hi) {
  return (unsigned int)f2bf(lo) | ((unsigned int)f2bf(hi) << 16);
}
__device__ __forceinline__ float4 add4(float4 a, float4 b) {
  return make_float4(a.x + b.x, a.y + b.y, a.z + b.z, a.w + b.w);
}
__device__ __forceinline__ f32x4 mfma16(bf16x8 a, bf16x8 b, f32x4 c) {
  return __builtin_amdgcn_mfma_f32_16x16x32_bf16(a, b, c, 0, 0, 0);
}

// ============================ CSR build ============================

__global__ void zero_deg(int* __restrict__ deg) {
  int i = blockIdx.x * 256 + threadIdx.x;
  if (i <= NN) deg[i] = 0;
}

__global__ void hist_kernel(const int* __restrict__ ei, int* __restrict__ deg) {
  int e = blockIdx.x * blockDim.x + threadIdx.x;
  if (e < NE) atomicAdd(&deg[ei[NE + e]], 1);
}

__global__ void scan1_kernel(const int* __restrict__ deg, int* __restrict__ rowptr,
                             int* __restrict__ bsums) {
  __shared__ int tile[256];
  int t = threadIdx.x, gid = blockIdx.x * 256 + t;
  int v = (gid < NN) ? deg[gid] : 0;
  tile[t] = v;
  __syncthreads();
  for (int off = 1; off < 256; off <<= 1) {
    int u = (t >= off) ? tile[t - off] : 0;
    __syncthreads();
    tile[t] += u;
    __syncthreads();
  }
  if (gid < NN) rowptr[gid] = tile[t] - v;
  if (t == 255) bsums[blockIdx.x] = tile[t];
}

__global__ void scan2_kernel(int* __restrict__ bsums, int nb) {
  __shared__ int tile[256];
  int t = threadIdx.x;
  int v = (t < nb) ? bsums[t] : 0;
  tile[t] = v;
  __syncthreads();
  for (int off = 1; off < 256; off <<= 1) {
    int u = (t >= off) ? tile[t - off] : 0;
    __syncthreads();
    tile[t] += u;
    __syncthreads();
  }
  if (t < nb) bsums[t] = tile[t] - v;
}

__global__ void scan3_kernel(int* __restrict__ rowptr, const int* __restrict__ bsums,
                             int* __restrict__ cursor) {
  int gid = blockIdx.x * 256 + threadIdx.x;
  if (gid < NN) {
    int r = rowptr[gid] + bsums[blockIdx.x];
    rowptr[gid] = r;
    cursor[gid] = r;
  } else if (gid == NN) {
    rowptr[NN] = NE;
  }
}

__global__ __launch_bounds__(256) void scatter_xcd(const int* __restrict__ ei,
                                                   int* __restrict__ cursor,
                                                   int* __restrict__ srcs) {
  int g = blockIdx.x & 7;
  int bid = blockIdx.x >> 3;
  int nb = gridDim.x >> 3;
  int lo = g * DPART, hi = lo + DPART;
  int stride = nb * 256;
  for (int e = bid * 256 + threadIdx.x; e < NE; e += stride) {
    int d = ei[NE + e];
    if (d >= lo && d < hi) {
      int pos = atomicAdd(&cursor[d], 1);
      srcs[pos] = ei[e];
    }
  }
}

// ============================ MFMA node GEMMs ============================
// Fragment conventions (16x16x32 bf16):
//   A: row = lane&15, k = (lane>>4)*8 + j; B: col = lane&15, same k
//   D: col = lane&15, row = (lane>>4)*4 + reg
// b-table split into b_lo/b_hi (channels 0-31 / 32-63), each 3.2MB so a full
// table fits in one XCD L2 during edge passes.

__global__ __launch_bounds__(256) void transform_dual(const float* __restrict__ feat,
                                                      const float* __restrict__ W,
                                                      float* __restrict__ a_tab,
                                                      ushort_t* __restrict__ b_lo,
                                                      ushort_t* __restrict__ b_hi) {
  __shared__ ushort_t wl[16 * 64 * 8];  // 16KB
  __shared__ ushort_t xs[64 * 64];      // 8KB, swizzled
  int t = threadIdx.x;
  int nbase = blockIdx.x * 64;

  for (int i = t; i < 8192; i += 256) {
    int c = i & 127, k = i >> 7;
    float v = W[((c >> 6) * 64 + k) * 64 + (c & 63)];
    int ct = c >> 4, lane = (c & 15) + ((k >> 3) & 3) * 16, kh = k >> 5;
    wl[((ct * 2 + kh) * 64 + lane) * 8 + (k & 7)] = f2bf(v);
  }
  {
    const float4* f4 = (const float4*)feat;
    uint2* x2 = (uint2*)xs;
    for (int i = t; i < 1024; i += 256) {
      int ni = i >> 4, c4 = i & 15;
      int node = nbase + ni;
      float4 v = make_float4(0.f, 0.f, 0.f, 0.f);
      if (node < NN) v = f4[(size_t)nbase * 16 + i];
      uint2 pk;
      pk.x = bfpack2(v.x, v.y);
      pk.y = bfpack2(v.z, v.w);
      x2[(ni * 16 + c4) ^ ((ni & 7) << 1)] = pk;
    }
  }
  __syncthreads();

  int wv = t >> 6, lane = t & 63;
  int lrow = wv * 16 + (lane & 15);
  const bf16x8* xf = (const bf16x8*)xs;
  bf16x8 a0 = xf[(lrow * 8 + (lane >> 4)) ^ (lrow & 7)];
  bf16x8 a1 = xf[(lrow * 8 + 4 + (lane >> 4)) ^ (lrow & 7)];
  const bf16x8* wf = (const bf16x8*)wl;

  f32x4 acc[8];
#pragma unroll
  for (int ct = 0; ct < 8; ++ct) {
    f32x4 c = {0.f, 0.f, 0.f, 0.f};
    c = mfma16(a0, wf[(ct * 2 + 0) * 64 + lane], c);
    c = mfma16(a1, wf[(ct * 2 + 1) * 64 + lane], c);
    acc[ct] = c;
  }

  int r0 = nbase + wv * 16 + (lane >> 4) * 4;
  int cl = lane & 15;
#pragma unroll
  for (int ct = 0; ct < 4; ++ct)
#pragma unroll
    for (int r = 0; r < 4; ++r) {
      int node = r0 + r;
      if (node < NN) a_tab[(size_t)node * 64 + ct * 16 + cl] = acc[ct][r];
    }
#pragma unroll
  for (int ct = 4; ct < 8; ++ct)
#pragma unroll
    for (int r = 0; r < 4; ++r) {
      int node = r0 + r;
      int c = (ct - 4) * 16 + cl;
      ushort_t* bt = (c < 32) ? b_lo : b_hi;
      if (node < NN) bt[(size_t)node * 32 + (c & 31)] = f2bf(acc[ct][r]);
    }
}

__global__ __launch_bounds__(256) void transform_fused(const float* __restrict__ agg,
                                                       const float* __restrict__ W2,
                                                       const float* __restrict__ b2,
                                                       const int* __restrict__ deg,
                                                       const float* __restrict__ W1,
                                                       float* __restrict__ a_tab,
                                                       ushort_t* __restrict__ b_lo,
                                                       ushort_t* __restrict__ b_hi) {
  __shared__ ushort_t w2l[8 * 64 * 8];
  __shared__ ushort_t w1l[16 * 64 * 8];
  __shared__ ushort_t xs[64 * 64];
  __shared__ ushort_t hs[64 * 64];
  int t = threadIdx.x;
  int nbase = blockIdx.x * 64;

  for (int i = t; i < 4096; i += 256) {
    int c = i & 63, k = i >> 6;
    float v = W2[k * 64 + c];
    int ct = c >> 4, lane = (c & 15) + ((k >> 3) & 3) * 16, kh = k >> 5;
    w2l[((ct * 2 + kh) * 64 + lane) * 8 + (k & 7)] = f2bf(v);
  }
  for (int i = t; i < 8192; i += 256) {
    int c = i & 127, k = i >> 7;
    float v = W1[((c >> 6) * 64 + k) * 64 + (c & 63)];
    int ct = c >> 4, lane = (c & 15) + ((k >> 3) & 3) * 16, kh = k >> 5;
    w1l[((ct * 2 + kh) * 64 + lane) * 8 + (k & 7)] = f2bf(v);
  }
  {
    const float4* f4 = (const float4*)agg;
    uint2* x2 = (uint2*)xs;
    for (int i = t; i < 1024; i += 256) {
      int ni = i >> 4, c4 = i & 15;
      int node = nbase + ni;
      float4 v = make_float4(0.f, 0.f, 0.f, 0.f);
      if (node < NN) v = f4[(size_t)nbase * 16 + i];
      uint2 pk;
      pk.x = bfpack2(v.x, v.y);
      pk.y = bfpack2(v.z, v.w);
      x2[(ni * 16 + c4) ^ ((ni & 7) << 1)] = pk;
    }
  }
  __syncthreads();

  int wv = t >> 6, lane = t & 63;
  int lrow = wv * 16 + (lane & 15);
  const bf16x8* xf = (const bf16x8*)xs;
  bf16x8 a0 = xf[(lrow * 8 + (lane >> 4)) ^ (lrow & 7)];
  bf16x8 a1 = xf[(lrow * 8 + 4 + (lane >> 4)) ^ (lrow & 7)];
  const bf16x8* w2f = (const bf16x8*)w2l;

  f32x4 hacc[4];
#pragma unroll
  for (int ct = 0; ct < 4; ++ct) {
    f32x4 c = {0.f, 0.f, 0.f, 0.f};
    c = mfma16(a0, w2f[(ct * 2 + 0) * 64 + lane], c);
    c = mfma16(a1, w2f[(ct * 2 + 1) * 64 + lane], c);
    hacc[ct] = c;
  }

  int r0 = nbase + wv * 16 + (lane >> 4) * 4;
  int lr0 = wv * 16 + (lane >> 4) * 4;
  int cl = lane & 15;
  float cnt[4];
#pragma unroll
  for (int r = 0; r < 4; ++r) {
    int node = r0 + r;
    cnt[r] = (node < NN) ? (float)(deg[node] + 1) : 0.f;
  }
#pragma unroll
  for (int ct = 0; ct < 4; ++ct) {
    float bv = b2[ct * 16 + cl];
#pragma unroll
    for (int r = 0; r < 4; ++r) {
      float h = fmaxf(hacc[ct][r] + cnt[r] * bv, 0.f);
      int lr = lr0 + r;
      hs[(lr * 64 + ct * 16 + cl) ^ ((lr & 7) << 3)] = f2bf(h);
    }
  }
  __syncthreads();

  const bf16x8* hf = (const bf16x8*)hs;
  bf16x8 h0 = hf[(lrow * 8 + (lane >> 4)) ^ (lrow & 7)];
  bf16x8 h1 = hf[(lrow * 8 + 4 + (lane >> 4)) ^ (lrow & 7)];
  const bf16x8* w1f = (const bf16x8*)w1l;

  f32x4 acc[8];
#pragma unroll
  for (int ct = 0; ct < 8; ++ct) {
    f32x4 c = {0.f, 0.f, 0.f, 0.f};
    c = mfma16(h0, w1f[(ct * 2 + 0) * 64 + lane], c);
    c = mfma16(h1, w1f[(ct * 2 + 1) * 64 + lane], c);
    acc[ct] = c;
  }
#pragma unroll
  for (int ct = 0; ct < 4; ++ct)
#pragma unroll
    for (int r = 0; r < 4; ++r) {
      int node = r0 + r;
      if (node < NN) a_tab[(size_t)node * 64 + ct * 16 + cl] = acc[ct][r];
    }
#pragma unroll
  for (int ct = 4; ct < 8; ++ct)
#pragma unroll
    for (int r = 0; r < 4; ++r) {
      int node = r0 + r;
      int c = (ct - 4) * 16 + cl;
      ushort_t* bt = (c < 32) ? b_lo : b_hi;
      if (node < NN) bt[(size_t)node * 32 + (c & 31)] = f2bf(acc[ct][r]);
    }
}

__global__ __launch_bounds__(256) void transform_single(const float* __restrict__ agg,
                                                        const float* __restrict__ W2,
                                                        const float* __restrict__ b2,
                                                        const int* __restrict__ deg,
                                                        float* __restrict__ out) {
  __shared__ ushort_t w2l[8 * 64 * 8];
  __shared__ ushort_t xs[64 * 64];
  int t = threadIdx.x;
  int nbase = blockIdx.x * 64;

  for (int i = t; i < 4096; i += 256) {
    int c = i & 63, k = i >> 6;
    float v = W2[k * 64 + c];
    int ct = c >> 4, lane = (c & 15) + ((k >> 3) & 3) * 16, kh = k >> 5;
    w2l[((ct * 2 + kh) * 64 + lane) * 8 + (k & 7)] = f2bf(v);
  }
  {
    const float4* f4 = (const float4*)agg;
    uint2* x2 = (uint2*)xs;
    for (int i = t; i < 1024; i += 256) {
      int ni = i >> 4, c4 = i & 15;
      int node = nbase + ni;
      float4 v = make_float4(0.f, 0.f, 0.f, 0.f);
      if (node < NN) v = f4[(size_t)nbase * 16 + i];
      uint2 pk;
      pk.x = bfpack2(v.x, v.y);
      pk.y = bfpack2(v.z, v.w);
      x2[(ni * 16 + c4) ^ ((ni & 7) << 1)] = pk;
    }
  }
  __syncthreads();

  int wv = t >> 6, lane = t & 63;
  int lrow = wv * 16 + (lane & 15);
  const bf16x8* xf = (const bf16x8*)xs;
  bf16x8 a0 = xf[(lrow * 8 + (lane >> 4)) ^ (lrow & 7)];
  bf16x8 a1 = xf[(lrow * 8 + 4 + (lane >> 4)) ^ (lrow & 7)];
  const bf16x8* w2f = (const bf16x8*)w2l;

  f32x4 acc[4];
#pragma unroll
  for (int ct = 0; ct < 4; ++ct) {
    f32x4 c = {0.f, 0.f, 0.f, 0.f};
    c = mfma16(a0, w2f[(ct * 2 + 0) * 64 + lane], c);
    c = mfma16(a1, w2f[(ct * 2 + 1) * 64 + lane], c);
    acc[ct] = c;
  }

  int r0 = nbase + wv * 16 + (lane >> 4) * 4;
  int cl = lane & 15;
  float cnt[4];
#pragma unroll
  for (int r = 0; r < 4; ++r) {
    int node = r0 + r;
    cnt[r] = (node < NN) ? (float)(deg[node] + 1) : 0.f;
  }
#pragma unroll
  for (int ct = 0; ct < 4; ++ct) {
    float bv = b2[ct * 16 + cl];
#pragma unroll
    for (int r = 0; r < 4; ++r) {
      int node = r0 + r;
      if (node < NN)
        out[(size_t)node * 64 + ct * 16 + cl] = fmaxf(acc[ct][r] + cnt[r] * bv, 0.f);
    }
  }
}

// ============================ edge aggregation (half-channel pass) ============================
// agg[n][coff..coff+31] = sum over in-edges+self of relu(a[n][c]+b1[c]+b_half[src][c-coff])
// b_half table = 3.2MB -> fits in one XCD L2. Wave: 8 slots x 8 lanes, 4 ch/lane.
__global__ __launch_bounds__(256) void edge_agg_half(const float* __restrict__ a_tab,
                                                     const ushort_t* __restrict__ b_half,
                                                     const int* __restrict__ rowptr,
                                                     const int* __restrict__ srcs,
                                                     const float* __restrict__ b1,
                                                     float* __restrict__ agg, int coff) {
  int node = blockIdx.x * 4 + (threadIdx.x >> 6);
  if (node >= NN) return;
  int lane = threadIdx.x & 63;
  int slot = lane >> 3;
  int c8 = lane & 7;
  int cbase = (coff >> 2) + c8;  // float4 index within 64-ch row

  const float4* a4 = (const float4*)a_tab;
  const float4* b14 = (const float4*)b1;
  const uint2* bt = (const uint2*)b_half;  // row = 8 uint2 (32 bf16)

  float4 an = add4(a4[(size_t)node * 16 + cbase], b14[cbase]);
  float4 acc = make_float4(0.f, 0.f, 0.f, 0.f);

  if (slot == 0) {  // self loop
    uint2 bv = bt[(size_t)node * 8 + c8];
    acc.x = fmaxf(an.x + __uint_as_float(bv.x << 16), 0.f);
    acc.y = fmaxf(an.y + __uint_as_float(bv.x & 0xFFFF0000u), 0.f);
    acc.z = fmaxf(an.z + __uint_as_float(bv.y << 16), 0.f);
    acc.w = fmaxf(an.w + __uint_as_float(bv.y & 0xFFFF0000u), 0.f);
  }

  int s0 = rowptr[node], s1 = rowptr[node + 1];
  for (int e = s0 + slot; e < s1; e += 8) {
    int s = srcs[e];
    uint2 bv = bt[(size_t)s * 8 + c8];
    acc.x += fmaxf(an.x + __uint_as_float(bv.x << 16), 0.f);
    acc.y += fmaxf(an.y + __uint_as_float(bv.x & 0xFFFF0000u), 0.f);
    acc.z += fmaxf(an.z + __uint_as_float(bv.y << 16), 0.f);
    acc.w += fmaxf(an.w + __uint_as_float(bv.y & 0xFFFF0000u), 0.f);
  }

#pragma unroll
  for (int m = 8; m <= 32; m <<= 1) {
    acc.x += __shfl_xor(acc.x, m, 64);
    acc.y += __shfl_xor(acc.y, m, 64);
    acc.z += __shfl_xor(acc.z, m, 64);
    acc.w += __shfl_xor(acc.w, m, 64);
  }
  if (slot == 0) {
    float4* agg4 = (float4*)agg;
    agg4[(size_t)node * 16 + cbase] = acc;
  }
}

// ============================ pooling + head ============================

__global__ void gstart_kernel(const int* __restrict__ batch, int* __restrict__ gstart) {
  int g = threadIdx.x;
  if (g > NG) return;
  int lo = 0, hi = NN;
  while (lo < hi) {
    int mid = (lo + hi) >> 1;
    if (batch[mid] < g) lo = mid + 1; else hi = mid;
  }
  gstart[g] = lo;
}

// 8 chunks/graph, direct writes (no zeroing, no atomics)
__global__ __launch_bounds__(256) void pool_partial(const float* __restrict__ h,
                                                    const int* __restrict__ gstart,
                                                    float* __restrict__ partials) {
  int g = blockIdx.x >> 3, q = blockIdx.x & 7;
  int lane = threadIdx.x & 63, w = threadIdx.x >> 6;
  int s = gstart[g], e = gstart[g + 1];
  int len = e - s;
  int qs = s + (len * q) / 8, qe = s + (len * (q + 1)) / 8;
  float a0 = 0.f, a1 = 0.f;
  int n = qs + w;
  for (; n + 4 < qe; n += 8) {
    a0 += h[(size_t)n * 64 + lane];
    a1 += h[(size_t)(n + 4) * 64 + lane];
  }
  for (; n < qe; n += 4) a0 += h[(size_t)n * 64 + lane];
  __shared__ float red[4][64];
  red[w][lane] = a0 + a1;
  __syncthreads();
  if (w == 0)
    partials[(size_t)(g * 8 + q) * 64 + lane] =
        red[0][lane] + red[1][lane] + red[2][lane] + red[3][lane];
}

__global__ void final_kernel(const float* __restrict__ partials, const int* __restrict__ gstart,
                             const float* __restrict__ Wl, const float* __restrict__ bl,
                             float* __restrict__ out) {
  int g = blockIdx.x;
  int t = threadIdx.x;  // 64
  __shared__ float pm[64];
  float inv = 1.f / fmaxf((float)(gstart[g + 1] - gstart[g]), 1.f);
  float s = 0.f;
#pragma unroll
  for (int q = 0; q < 8; ++q) s += partials[(size_t)(g * 8 + q) * 64 + t];
  pm[t] = s * inv;
  __syncthreads();
  float acc = bl[t];
  for (int k = 0; k < 64; ++k) acc += pm[k] * Wl[k * 64 + t];
  out[g * 64 + t] = acc;
}

// ============================ launch ============================

extern "C" void kernel_launch(void* const* d_in, const int* in_sizes, int n_in,
                              void* d_out, int out_size, void* d_ws, size_t ws_size,
                              hipStream_t stream) {
  const float* x = (const float*)d_in[0];
  const int* ei = (const int*)d_in[1];
  const int* batch = (const int*)d_in[2];
  const float* W1a = (const float*)d_in[3];
  const float* b1a = (const float*)d_in[4];
  const float* W2a = (const float*)d_in[5];
  const float* b2a = (const float*)d_in[6];
  const float* W1b = (const float*)d_in[7];
  const float* b1b = (const float*)d_in[8];
  const float* W2b = (const float*)d_in[9];
  const float* b2b = (const float*)d_in[10];
  const float* Wl = (const float*)d_in[11];
  const float* bl = (const float*)d_in[12];
  float* out = (float*)d_out;

  char* p = (char*)d_ws;
  auto alloc = [&](size_t bytes) {
    char* r = p;
    p += (bytes + 255) & ~(size_t)255;
    return r;
  };
  int* deg = (int*)alloc((NN + 1) * sizeof(int));
  int* rowptr = (int*)alloc((NN + 1) * sizeof(int));
  int* cursor = (int*)alloc(NN * sizeof(int));
  int* bsums = (int*)alloc(256 * sizeof(int));
  int* gstart = (int*)alloc((NG + 1) * sizeof(int));
  int* srcs = (int*)alloc((size_t)NE * sizeof(int));
  float* a_tab = (float*)alloc((size_t)NN * 64 * sizeof(float));
  ushort_t* b_lo = (ushort_t*)alloc((size_t)NN * 32 * sizeof(ushort_t));
  ushort_t* b_hi = (ushort_t*)alloc((size_t)NN * 32 * sizeof(ushort_t));
  float* hbuf = (float*)alloc((size_t)NN * 64 * sizeof(float));
  float* partials = (float*)alloc((size_t)NG * 8 * 64 * sizeof(float));

  zero_deg<<<(NN + 256) / 256, 256, 0, stream>>>(deg);
  hist_kernel<<<(NE + 255) / 256, 256, 0, stream>>>(ei, deg);
  scan1_kernel<<<196, 256, 0, stream>>>(deg, rowptr, bsums);
  scan2_kernel<<<1, 256, 0, stream>>>(bsums, 196);
  scan3_kernel<<<196, 256, 0, stream>>>(rowptr, bsums, cursor);
  scatter_xcd<<<1024, 256, 0, stream>>>(ei, cursor, srcs);
  gstart_kernel<<<1, 128, 0, stream>>>(batch, gstart);

  int tb = (NN + 63) / 64;   // 782
  int eb = (NN + 3) / 4;     // 12500
  // layer 1
  transform_dual<<<tb, 256, 0, stream>>>(x, W1a, a_tab, b_lo, b_hi);
  edge_agg_half<<<eb, 256, 0, stream>>>(a_tab, b_lo, rowptr, srcs, b1a, hbuf, 0);
  edge_agg_half<<<eb, 256, 0, stream>>>(a_tab, b_hi, rowptr, srcs, b1a, hbuf, 32);
  // fused: layer1 epilogue + layer2 tables (h1 stays on-chip)
  transform_fused<<<tb, 256, 0, stream>>>(hbuf, W2a, b2a, deg, W1b, a_tab, b_lo, b_hi);
  edge_agg_half<<<eb, 256, 0, stream>>>(a_tab, b_lo, rowptr, srcs, b1b, hbuf, 0);
  edge_agg_half<<<eb, 256, 0, stream>>>(a_tab, b_hi, rowptr, srcs, b1b, hbuf, 32);
  transform_single<<<tb, 256, 0, stream>>>(hbuf, W2b, b2b, deg, hbuf);
  // pool + head
  pool_partial<<<NG * 8, 256, 0, stream>>>(hbuf, gstart, partials);
  final_kernel<<<NG, 64, 0, stream>>>(partials, gstart, Wl, bl, out);
}

// Round 8
// 193.443 us; speedup vs baseline: 1.2341x; 1.2341x over previous
//
#include <hip/hip_runtime.h>

#define NN 50000
#define NE 800000
#define NG 64
#define DPART (NN / 8)

typedef float f32x4 __attribute__((ext_vector_type(4)));
typedef short bf16x8 __attribute__((ext_vector_type(8)));
typedef unsigned short ushort_t;

__device__ __forceinline__ ushort_t f2bf(float x) {
  unsigned int u = __float_as_uint(x);
  u = (u + 0x7FFFu + ((u >> 16) & 1u)) >> 16;
  return (ushort_t)u;
}
__device__ __forceinline__ unsigned int bfpack2(float lo, float hi) {
  return (unsigned int)f2bf(lo) | ((unsigned int)f2bf(hi) << 16);
}
__device__ __forceinline__ float4 add4(float4 a, float4 b) {
  return make_float4(a.x + b.x, a.y + b.y, a.z + b.z, a.w + b.w);
}
__device__ __forceinline__ f32x4 mfma16(bf16x8 a, bf16x8 b, f32x4 c) {
  return __builtin_amdgcn_mfma_f32_16x16x32_bf16(a, b, c, 0, 0, 0);
}

// ============================ setup (deg zero + graph starts) ============================

__global__ void setup_kernel(const int* __restrict__ batch, int* __restrict__ deg,
                             int* __restrict__ gstart) {
  int i = blockIdx.x * 256 + threadIdx.x;
  if (i <= NN) deg[i] = 0;
  if (blockIdx.x == 0 && threadIdx.x <= NG) {
    int g = threadIdx.x;
    int lo = 0, hi = NN;
    while (lo < hi) {
      int mid = (lo + hi) >> 1;
      if (batch[mid] < g) lo = mid + 1; else hi = mid;
    }
    gstart[g] = lo;
  }
}

// ============================ CSR build ============================

__global__ void hist_kernel(const int* __restrict__ ei, int* __restrict__ deg) {
  int e = blockIdx.x * blockDim.x + threadIdx.x;
  if (e < NE) atomicAdd(&deg[ei[NE + e]], 1);
}

__global__ void scan1_kernel(const int* __restrict__ deg, int* __restrict__ rowptr,
                             int* __restrict__ bsums) {
  __shared__ int tile[256];
  int t = threadIdx.x, gid = blockIdx.x * 256 + t;
  int v = (gid < NN) ? deg[gid] : 0;
  tile[t] = v;
  __syncthreads();
  for (int off = 1; off < 256; off <<= 1) {
    int u = (t >= off) ? tile[t - off] : 0;
    __syncthreads();
    tile[t] += u;
    __syncthreads();
  }
  if (gid < NN) rowptr[gid] = tile[t] - v;
  if (t == 255) bsums[blockIdx.x] = tile[t];
}

__global__ void scan2_kernel(int* __restrict__ bsums, int nb) {
  __shared__ int tile[256];
  int t = threadIdx.x;
  int v = (t < nb) ? bsums[t] : 0;
  tile[t] = v;
  __syncthreads();
  for (int off = 1; off < 256; off <<= 1) {
    int u = (t >= off) ? tile[t - off] : 0;
    __syncthreads();
    tile[t] += u;
    __syncthreads();
  }
  if (t < nb) bsums[t] = tile[t] - v;
}

__global__ void scan3_kernel(int* __restrict__ rowptr, const int* __restrict__ bsums,
                             int* __restrict__ cursor) {
  int gid = blockIdx.x * 256 + threadIdx.x;
  if (gid < NN) {
    int r = rowptr[gid] + bsums[blockIdx.x];
    rowptr[gid] = r;
    cursor[gid] = r;
  } else if (gid == NN) {
    rowptr[NN] = NE;
  }
}

// XCD-partitioned scatter (kills write amplification; correct under any mapping)
__global__ __launch_bounds__(256) void scatter_xcd(const int* __restrict__ ei,
                                                   int* __restrict__ cursor,
                                                   int* __restrict__ srcs) {
  int g = blockIdx.x & 7;
  int bid = blockIdx.x >> 3;
  int nb = gridDim.x >> 3;
  int lo = g * DPART, hi = lo + DPART;
  int stride = nb * 256;
  for (int e = bid * 256 + threadIdx.x; e < NE; e += stride) {
    int d = ei[NE + e];
    if (d >= lo && d < hi) {
      int pos = atomicAdd(&cursor[d], 1);
      srcs[pos] = ei[e];
    }
  }
}

// ============================ MFMA node GEMMs ============================
// Fragment conventions (16x16x32 bf16):
//   A: row = lane&15, k = (lane>>4)*8 + j; B: col = lane&15, same k
//   D: col = lane&15, row = (lane>>4)*4 + reg

__global__ __launch_bounds__(256) void transform_dual(const float* __restrict__ feat,
                                                      const float* __restrict__ W,
                                                      float* __restrict__ a_tab,
                                                      ushort_t* __restrict__ b_tab) {
  __shared__ ushort_t wl[16 * 64 * 8];  // 16KB
  __shared__ ushort_t xs[64 * 64];      // 8KB, swizzled
  int t = threadIdx.x;
  int nbase = blockIdx.x * 64;

  for (int i = t; i < 8192; i += 256) {
    int c = i & 127, k = i >> 7;
    float v = W[((c >> 6) * 64 + k) * 64 + (c & 63)];
    int ct = c >> 4, lane = (c & 15) + ((k >> 3) & 3) * 16, kh = k >> 5;
    wl[((ct * 2 + kh) * 64 + lane) * 8 + (k & 7)] = f2bf(v);
  }
  {
    const float4* f4 = (const float4*)feat;
    uint2* x2 = (uint2*)xs;
    for (int i = t; i < 1024; i += 256) {
      int ni = i >> 4, c4 = i & 15;
      int node = nbase + ni;
      float4 v = make_float4(0.f, 0.f, 0.f, 0.f);
      if (node < NN) v = f4[(size_t)nbase * 16 + i];
      uint2 pk;
      pk.x = bfpack2(v.x, v.y);
      pk.y = bfpack2(v.z, v.w);
      x2[(ni * 16 + c4) ^ ((ni & 7) << 1)] = pk;
    }
  }
  __syncthreads();

  int wv = t >> 6, lane = t & 63;
  int lrow = wv * 16 + (lane & 15);
  const bf16x8* xf = (const bf16x8*)xs;
  bf16x8 a0 = xf[(lrow * 8 + (lane >> 4)) ^ (lrow & 7)];
  bf16x8 a1 = xf[(lrow * 8 + 4 + (lane >> 4)) ^ (lrow & 7)];
  const bf16x8* wf = (const bf16x8*)wl;

  f32x4 acc[8];
#pragma unroll
  for (int ct = 0; ct < 8; ++ct) {
    f32x4 c = {0.f, 0.f, 0.f, 0.f};
    c = mfma16(a0, wf[(ct * 2 + 0) * 64 + lane], c);
    c = mfma16(a1, wf[(ct * 2 + 1) * 64 + lane], c);
    acc[ct] = c;
  }

  int r0 = nbase + wv * 16 + (lane >> 4) * 4;
  int cl = lane & 15;
#pragma unroll
  for (int ct = 0; ct < 4; ++ct)
#pragma unroll
    for (int r = 0; r < 4; ++r) {
      int node = r0 + r;
      if (node < NN) a_tab[(size_t)node * 64 + ct * 16 + cl] = acc[ct][r];
    }
#pragma unroll
  for (int ct = 4; ct < 8; ++ct)
#pragma unroll
    for (int r = 0; r < 4; ++r) {
      int node = r0 + r;
      if (node < NN) b_tab[(size_t)node * 64 + (ct - 4) * 16 + cl] = f2bf(acc[ct][r]);
    }
}

__global__ __launch_bounds__(256) void transform_fused(const float* __restrict__ agg,
                                                       const float* __restrict__ W2,
                                                       const float* __restrict__ b2,
                                                       const int* __restrict__ deg,
                                                       const float* __restrict__ W1,
                                                       float* __restrict__ a_tab,
                                                       ushort_t* __restrict__ b_tab) {
  __shared__ ushort_t w2l[8 * 64 * 8];
  __shared__ ushort_t w1l[16 * 64 * 8];
  __shared__ ushort_t xs[64 * 64];
  __shared__ ushort_t hs[64 * 64];
  int t = threadIdx.x;
  int nbase = blockIdx.x * 64;

  for (int i = t; i < 4096; i += 256) {
    int c = i & 63, k = i >> 6;
    float v = W2[k * 64 + c];
    int ct = c >> 4, lane = (c & 15) + ((k >> 3) & 3) * 16, kh = k >> 5;
    w2l[((ct * 2 + kh) * 64 + lane) * 8 + (k & 7)] = f2bf(v);
  }
  for (int i = t; i < 8192; i += 256) {
    int c = i & 127, k = i >> 7;
    float v = W1[((c >> 6) * 64 + k) * 64 + (c & 63)];
    int ct = c >> 4, lane = (c & 15) + ((k >> 3) & 3) * 16, kh = k >> 5;
    w1l[((ct * 2 + kh) * 64 + lane) * 8 + (k & 7)] = f2bf(v);
  }
  {
    const float4* f4 = (const float4*)agg;
    uint2* x2 = (uint2*)xs;
    for (int i = t; i < 1024; i += 256) {
      int ni = i >> 4, c4 = i & 15;
      int node = nbase + ni;
      float4 v = make_float4(0.f, 0.f, 0.f, 0.f);
      if (node < NN) v = f4[(size_t)nbase * 16 + i];
      uint2 pk;
      pk.x = bfpack2(v.x, v.y);
      pk.y = bfpack2(v.z, v.w);
      x2[(ni * 16 + c4) ^ ((ni & 7) << 1)] = pk;
    }
  }
  __syncthreads();

  int wv = t >> 6, lane = t & 63;
  int lrow = wv * 16 + (lane & 15);
  const bf16x8* xf = (const bf16x8*)xs;
  bf16x8 a0 = xf[(lrow * 8 + (lane >> 4)) ^ (lrow & 7)];
  bf16x8 a1 = xf[(lrow * 8 + 4 + (lane >> 4)) ^ (lrow & 7)];
  const bf16x8* w2f = (const bf16x8*)w2l;

  f32x4 hacc[4];
#pragma unroll
  for (int ct = 0; ct < 4; ++ct) {
    f32x4 c = {0.f, 0.f, 0.f, 0.f};
    c = mfma16(a0, w2f[(ct * 2 + 0) * 64 + lane], c);
    c = mfma16(a1, w2f[(ct * 2 + 1) * 64 + lane], c);
    hacc[ct] = c;
  }

  int r0 = nbase + wv * 16 + (lane >> 4) * 4;
  int lr0 = wv * 16 + (lane >> 4) * 4;
  int cl = lane & 15;
  float cnt[4];
#pragma unroll
  for (int r = 0; r < 4; ++r) {
    int node = r0 + r;
    cnt[r] = (node < NN) ? (float)(deg[node] + 1) : 0.f;
  }
#pragma unroll
  for (int ct = 0; ct < 4; ++ct) {
    float bv = b2[ct * 16 + cl];
#pragma unroll
    for (int r = 0; r < 4; ++r) {
      float h = fmaxf(hacc[ct][r] + cnt[r] * bv, 0.f);
      int lr = lr0 + r;
      hs[(lr * 64 + ct * 16 + cl) ^ ((lr & 7) << 3)] = f2bf(h);
    }
  }
  __syncthreads();

  const bf16x8* hf = (const bf16x8*)hs;
  bf16x8 h0 = hf[(lrow * 8 + (lane >> 4)) ^ (lrow & 7)];
  bf16x8 h1 = hf[(lrow * 8 + 4 + (lane >> 4)) ^ (lrow & 7)];
  const bf16x8* w1f = (const bf16x8*)w1l;

  f32x4 acc[8];
#pragma unroll
  for (int ct = 0; ct < 8; ++ct) {
    f32x4 c = {0.f, 0.f, 0.f, 0.f};
    c = mfma16(h0, w1f[(ct * 2 + 0) * 64 + lane], c);
    c = mfma16(h1, w1f[(ct * 2 + 1) * 64 + lane], c);
    acc[ct] = c;
  }
#pragma unroll
  for (int ct = 0; ct < 4; ++ct)
#pragma unroll
    for (int r = 0; r < 4; ++r) {
      int node = r0 + r;
      if (node < NN) a_tab[(size_t)node * 64 + ct * 16 + cl] = acc[ct][r];
    }
#pragma unroll
  for (int ct = 4; ct < 8; ++ct)
#pragma unroll
    for (int r = 0; r < 4; ++r) {
      int node = r0 + r;
      if (node < NN) b_tab[(size_t)node * 64 + (ct - 4) * 16 + cl] = f2bf(acc[ct][r]);
    }
}

__global__ __launch_bounds__(256) void transform_single(const float* __restrict__ agg,
                                                        const float* __restrict__ W2,
                                                        const float* __restrict__ b2,
                                                        const int* __restrict__ deg,
                                                        float* __restrict__ out) {
  __shared__ ushort_t w2l[8 * 64 * 8];
  __shared__ ushort_t xs[64 * 64];
  int t = threadIdx.x;
  int nbase = blockIdx.x * 64;

  for (int i = t; i < 4096; i += 256) {
    int c = i & 63, k = i >> 6;
    float v = W2[k * 64 + c];
    int ct = c >> 4, lane = (c & 15) + ((k >> 3) & 3) * 16, kh = k >> 5;
    w2l[((ct * 2 + kh) * 64 + lane) * 8 + (k & 7)] = f2bf(v);
  }
  {
    const float4* f4 = (const float4*)agg;
    uint2* x2 = (uint2*)xs;
    for (int i = t; i < 1024; i += 256) {
      int ni = i >> 4, c4 = i & 15;
      int node = nbase + ni;
      float4 v = make_float4(0.f, 0.f, 0.f, 0.f);
      if (node < NN) v = f4[(size_t)nbase * 16 + i];
      uint2 pk;
      pk.x = bfpack2(v.x, v.y);
      pk.y = bfpack2(v.z, v.w);
      x2[(ni * 16 + c4) ^ ((ni & 7) << 1)] = pk;
    }
  }
  __syncthreads();

  int wv = t >> 6, lane = t & 63;
  int lrow = wv * 16 + (lane & 15);
  const bf16x8* xf = (const bf16x8*)xs;
  bf16x8 a0 = xf[(lrow * 8 + (lane >> 4)) ^ (lrow & 7)];
  bf16x8 a1 = xf[(lrow * 8 + 4 + (lane >> 4)) ^ (lrow & 7)];
  const bf16x8* w2f = (const bf16x8*)w2l;

  f32x4 acc[4];
#pragma unroll
  for (int ct = 0; ct < 4; ++ct) {
    f32x4 c = {0.f, 0.f, 0.f, 0.f};
    c = mfma16(a0, w2f[(ct * 2 + 0) * 64 + lane], c);
    c = mfma16(a1, w2f[(ct * 2 + 1) * 64 + lane], c);
    acc[ct] = c;
  }

  int r0 = nbase + wv * 16 + (lane >> 4) * 4;
  int cl = lane & 15;
  float cnt[4];
#pragma unroll
  for (int r = 0; r < 4; ++r) {
    int node = r0 + r;
    cnt[r] = (node < NN) ? (float)(deg[node] + 1) : 0.f;
  }
#pragma unroll
  for (int ct = 0; ct < 4; ++ct) {
    float bv = b2[ct * 16 + cl];
#pragma unroll
    for (int r = 0; r < 4; ++r) {
      int node = r0 + r;
      if (node < NN)
        out[(size_t)node * 64 + ct * 16 + cl] = fmaxf(acc[ct][r] + cnt[r] * bv, 0.f);
    }
  }
}

// ============================ edge aggregation ============================
// agg[n][c] = sum over in-edges+self of relu(a[n][c]+b1[c]+b_bf16[src][c])
// Wave: 8 slots x 8 lanes (16B/lane); edge loop unrolled x2 for latency hiding.
__device__ __forceinline__ void acc_row(float4& acc0, float4& acc1, const float4& an0,
                                        const float4& an1, uint4 bv) {
  acc0.x += fmaxf(an0.x + __uint_as_float(bv.x << 16), 0.f);
  acc0.y += fmaxf(an0.y + __uint_as_float(bv.x & 0xFFFF0000u), 0.f);
  acc0.z += fmaxf(an0.z + __uint_as_float(bv.y << 16), 0.f);
  acc0.w += fmaxf(an0.w + __uint_as_float(bv.y & 0xFFFF0000u), 0.f);
  acc1.x += fmaxf(an1.x + __uint_as_float(bv.z << 16), 0.f);
  acc1.y += fmaxf(an1.y + __uint_as_float(bv.z & 0xFFFF0000u), 0.f);
  acc1.z += fmaxf(an1.z + __uint_as_float(bv.w << 16), 0.f);
  acc1.w += fmaxf(an1.w + __uint_as_float(bv.w & 0xFFFF0000u), 0.f);
}

__global__ __launch_bounds__(256) void edge_agg(const float* __restrict__ a_tab,
                                                const ushort_t* __restrict__ b_tab,
                                                const int* __restrict__ rowptr,
                                                const int* __restrict__ srcs,
                                                const float* __restrict__ b1,
                                                float* __restrict__ agg) {
  int node = blockIdx.x * 4 + (threadIdx.x >> 6);
  if (node >= NN) return;
  int lane = threadIdx.x & 63;
  int slot = lane >> 3;
  int c8 = lane & 7;

  const float4* a4 = (const float4*)a_tab;
  const float4* b14 = (const float4*)b1;
  const uint4* bt = (const uint4*)b_tab;

  float4 an0 = add4(a4[(size_t)node * 16 + c8 * 2], b14[c8 * 2]);
  float4 an1 = add4(a4[(size_t)node * 16 + c8 * 2 + 1], b14[c8 * 2 + 1]);

  float4 acc0 = make_float4(0.f, 0.f, 0.f, 0.f);
  float4 acc1 = make_float4(0.f, 0.f, 0.f, 0.f);

  if (slot == 0) {  // self loop
    uint4 bv = bt[(unsigned)(node * 8 + c8)];
    acc_row(acc0, acc1, an0, an1, bv);
  }

  int s0 = rowptr[node], s1 = rowptr[node + 1];
  int e = s0 + slot;
  for (; e + 8 < s1; e += 16) {  // two edges in flight
    int sA = srcs[e], sB = srcs[e + 8];
    uint4 bvA = bt[(unsigned)(sA * 8 + c8)];
    uint4 bvB = bt[(unsigned)(sB * 8 + c8)];
    acc_row(acc0, acc1, an0, an1, bvA);
    acc_row(acc0, acc1, an0, an1, bvB);
  }
  for (; e < s1; e += 8) {
    int s = srcs[e];
    uint4 bv = bt[(unsigned)(s * 8 + c8)];
    acc_row(acc0, acc1, an0, an1, bv);
  }

#pragma unroll
  for (int m = 8; m <= 32; m <<= 1) {
    acc0.x += __shfl_xor(acc0.x, m, 64);
    acc0.y += __shfl_xor(acc0.y, m, 64);
    acc0.z += __shfl_xor(acc0.z, m, 64);
    acc0.w += __shfl_xor(acc0.w, m, 64);
    acc1.x += __shfl_xor(acc1.x, m, 64);
    acc1.y += __shfl_xor(acc1.y, m, 64);
    acc1.z += __shfl_xor(acc1.z, m, 64);
    acc1.w += __shfl_xor(acc1.w, m, 64);
  }
  if (slot == 0) {
    float4* agg4 = (float4*)agg;
    agg4[(size_t)node * 16 + c8 * 2] = acc0;
    agg4[(size_t)node * 16 + c8 * 2 + 1] = acc1;
  }
}

// ============================ pooling + head ============================

// 8 chunks/graph, direct writes (no zeroing, no atomics)
__global__ __launch_bounds__(256) void pool_partial(const float* __restrict__ h,
                                                    const int* __restrict__ gstart,
                                                    float* __restrict__ partials) {
  int g = blockIdx.x >> 3, q = blockIdx.x & 7;
  int lane = threadIdx.x & 63, w = threadIdx.x >> 6;
  int s = gstart[g], e = gstart[g + 1];
  int len = e - s;
  int qs = s + (len * q) / 8, qe = s + (len * (q + 1)) / 8;
  float a0 = 0.f, a1 = 0.f;
  int n = qs + w;
  for (; n + 4 < qe; n += 8) {
    a0 += h[(size_t)n * 64 + lane];
    a1 += h[(size_t)(n + 4) * 64 + lane];
  }
  for (; n < qe; n += 4) a0 += h[(size_t)n * 64 + lane];
  __shared__ float red[4][64];
  red[w][lane] = a0 + a1;
  __syncthreads();
  if (w == 0)
    partials[(size_t)(g * 8 + q) * 64 + lane] =
        red[0][lane] + red[1][lane] + red[2][lane] + red[3][lane];
}

__global__ void final_kernel(const float* __restrict__ partials, const int* __restrict__ gstart,
                             const float* __restrict__ Wl, const float* __restrict__ bl,
                             float* __restrict__ out) {
  int g = blockIdx.x;
  int t = threadIdx.x;  // 64
  __shared__ float pm[64];
  float inv = 1.f / fmaxf((float)(gstart[g + 1] - gstart[g]), 1.f);
  float s = 0.f;
#pragma unroll
  for (int q = 0; q < 8; ++q) s += partials[(size_t)(g * 8 + q) * 64 + t];
  pm[t] = s * inv;
  __syncthreads();
  float acc = bl[t];
  for (int k = 0; k < 64; ++k) acc += pm[k] * Wl[k * 64 + t];
  out[g * 64 + t] = acc;
}

// ============================ launch ============================

extern "C" void kernel_launch(void* const* d_in, const int* in_sizes, int n_in,
                              void* d_out, int out_size, void* d_ws, size_t ws_size,
                              hipStream_t stream) {
  const float* x = (const float*)d_in[0];
  const int* ei = (const int*)d_in[1];
  const int* batch = (const int*)d_in[2];
  const float* W1a = (const float*)d_in[3];
  const float* b1a = (const float*)d_in[4];
  const float* W2a = (const float*)d_in[5];
  const float* b2a = (const float*)d_in[6];
  const float* W1b = (const float*)d_in[7];
  const float* b1b = (const float*)d_in[8];
  const float* W2b = (const float*)d_in[9];
  const float* b2b = (const float*)d_in[10];
  const float* Wl = (const float*)d_in[11];
  const float* bl = (const float*)d_in[12];
  float* out = (float*)d_out;

  char* p = (char*)d_ws;
  auto alloc = [&](size_t bytes) {
    char* r = p;
    p += (bytes + 255) & ~(size_t)255;
    return r;
  };
  int* deg = (int*)alloc((NN + 1) * sizeof(int));
  int* rowptr = (int*)alloc((NN + 1) * sizeof(int));
  int* cursor = (int*)alloc(NN * sizeof(int));
  int* bsums = (int*)alloc(256 * sizeof(int));
  int* gstart = (int*)alloc((NG + 1) * sizeof(int));
  int* srcs = (int*)alloc((size_t)NE * sizeof(int));
  float* a_tab = (float*)alloc((size_t)NN * 64 * sizeof(float));
  ushort_t* b_tab = (ushort_t*)alloc((size_t)NN * 64 * sizeof(ushort_t));
  float* hbuf = (float*)alloc((size_t)NN * 64 * sizeof(float));
  float* partials = (float*)alloc((size_t)NG * 8 * 64 * sizeof(float));

  setup_kernel<<<(NN + 256) / 256, 256, 0, stream>>>(batch, deg, gstart);
  hist_kernel<<<(NE + 255) / 256, 256, 0, stream>>>(ei, deg);
  scan1_kernel<<<196, 256, 0, stream>>>(deg, rowptr, bsums);
  scan2_kernel<<<1, 256, 0, stream>>>(bsums, 196);
  scan3_kernel<<<196, 256, 0, stream>>>(rowptr, bsums, cursor);
  scatter_xcd<<<1024, 256, 0, stream>>>(ei, cursor, srcs);

  int tb = (NN + 63) / 64;  // 782
  int eb = (NN + 3) / 4;    // 12500
  // layer 1
  transform_dual<<<tb, 256, 0, stream>>>(x, W1a, a_tab, b_tab);
  edge_agg<<<eb, 256, 0, stream>>>(a_tab, b_tab, rowptr, srcs, b1a, hbuf);
  // fused: layer1 epilogue + layer2 tables (h1 stays on-chip)
  transform_fused<<<tb, 256, 0, stream>>>(hbuf, W2a, b2a, deg, W1b, a_tab, b_tab);
  edge_agg<<<eb, 256, 0, stream>>>(a_tab, b_tab, rowptr, srcs, b1b, hbuf);
  transform_single<<<tb, 256, 0, stream>>>(hbuf, W2b, b2b, deg, hbuf);
  // pool + head
  pool_partial<<<NG * 8, 256, 0, stream>>>(hbuf, gstart, partials);
  final_kernel<<<NG, 64, 0, stream>>>(partials, gstart, Wl, bl, out);
}

// Round 9
// 136.247 us; speedup vs baseline: 1.7522x; 1.4198x over previous
//
#include <hip/hip_runtime.h>

#define NN 50000
#define NE 800000
#define NG 64
#define CAP 48      // fixed bucket capacity; P[Poisson(16) >= 48] ~ 1e-11
#define OVCAP 4096  // overflow list capacity (correctness fallback)

typedef float f32x4 __attribute__((ext_vector_type(4)));
typedef short bf16x8 __attribute__((ext_vector_type(8)));
typedef unsigned short ushort_t;

__device__ __forceinline__ ushort_t f2bf(float x) {
  unsigned int u = __float_as_uint(x);
  u = (u + 0x7FFFu + ((u >> 16) & 1u)) >> 16;
  return (ushort_t)u;
}
__device__ __forceinline__ unsigned int bfpack2(float lo, float hi) {
  return (unsigned int)f2bf(lo) | ((unsigned int)f2bf(hi) << 16);
}
__device__ __forceinline__ float4 add4(float4 a, float4 b) {
  return make_float4(a.x + b.x, a.y + b.y, a.z + b.z, a.w + b.w);
}
__device__ __forceinline__ f32x4 mfma16(bf16x8 a, bf16x8 b, f32x4 c) {
  return __builtin_amdgcn_mfma_f32_16x16x32_bf16(a, b, c, 0, 0, 0);
}

// ============================ setup: zero cnt + graph starts ============================

__global__ void setup_kernel(const int* __restrict__ batch, int* __restrict__ cnt,
                             int* __restrict__ gstart) {
  int i = blockIdx.x * 256 + threadIdx.x;
  if (i <= NN) cnt[i] = 0;  // cnt[NN] = overflow counter
  if (blockIdx.x == 0 && threadIdx.x <= NG) {
    int g = threadIdx.x;
    int lo = 0, hi = NN;
    while (lo < hi) {
      int mid = (lo + hi) >> 1;
      if (batch[mid] < g) lo = mid + 1; else hi = mid;
    }
    gstart[g] = lo;
  }
}

// ============================ fused bucket-scatter + transform_dual ============================
// blocks [0,1024): XCD-partitioned fixed-bucket scatter (no hist/scan needed)
// blocks [1024,1806): MFMA dual transform of x -> a_tab (f32) + b_tab (bf16)
__global__ __launch_bounds__(256) void scatter_dual(const int* __restrict__ ei,
                                                    int* __restrict__ cnt,
                                                    int* __restrict__ srcs,
                                                    int* __restrict__ ov,
                                                    const float* __restrict__ feat,
                                                    const float* __restrict__ W,
                                                    float* __restrict__ a_tab,
                                                    ushort_t* __restrict__ b_tab) {
  __shared__ ushort_t wl[16 * 64 * 8];  // 16KB (dual path only)
  __shared__ ushort_t xs[64 * 64];      // 8KB, swizzled
  int t = threadIdx.x;

  if (blockIdx.x < 1024) {
    // ---- scatter path: partition g owns dst range [g*DP, (g+1)*DP) ----
    const int DP = NN / 8;
    int g = blockIdx.x & 7;
    int bid = blockIdx.x >> 3;  // 0..127
    int lo = g * DP, hi = lo + DP;
    for (int e = bid * 256 + t; e < NE; e += 128 * 256) {
      int d = ei[NE + e];
      if (d >= lo && d < hi) {
        int pos = atomicAdd(&cnt[d], 1);
        if (pos < CAP) {
          srcs[d * CAP + pos] = ei[e];
        } else {
          int op = atomicAdd(&cnt[NN], 1);
          if (op < OVCAP) {
            ov[2 * op] = d;
            ov[2 * op + 1] = ei[e];
          }
        }
      }
    }
    return;
  }

  // ---- dual transform path ----
  int nbase = (blockIdx.x - 1024) * 64;

  for (int i = t; i < 8192; i += 256) {
    int c = i & 127, k = i >> 7;
    float v = W[((c >> 6) * 64 + k) * 64 + (c & 63)];
    int ct = c >> 4, lane = (c & 15) + ((k >> 3) & 3) * 16, kh = k >> 5;
    wl[((ct * 2 + kh) * 64 + lane) * 8 + (k & 7)] = f2bf(v);
  }
  {
    const float4* f4 = (const float4*)feat;
    uint2* x2 = (uint2*)xs;
    for (int i = t; i < 1024; i += 256) {
      int ni = i >> 4, c4 = i & 15;
      int node = nbase + ni;
      float4 v = make_float4(0.f, 0.f, 0.f, 0.f);
      if (node < NN) v = f4[(size_t)nbase * 16 + i];
      uint2 pk;
      pk.x = bfpack2(v.x, v.y);
      pk.y = bfpack2(v.z, v.w);
      x2[(ni * 16 + c4) ^ ((ni & 7) << 1)] = pk;
    }
  }
  __syncthreads();

  int wv = t >> 6, lane = t & 63;
  int lrow = wv * 16 + (lane & 15);
  const bf16x8* xf = (const bf16x8*)xs;
  bf16x8 a0 = xf[(lrow * 8 + (lane >> 4)) ^ (lrow & 7)];
  bf16x8 a1 = xf[(lrow * 8 + 4 + (lane >> 4)) ^ (lrow & 7)];
  const bf16x8* wf = (const bf16x8*)wl;

  f32x4 acc[8];
#pragma unroll
  for (int ct = 0; ct < 8; ++ct) {
    f32x4 c = {0.f, 0.f, 0.f, 0.f};
    c = mfma16(a0, wf[(ct * 2 + 0) * 64 + lane], c);
    c = mfma16(a1, wf[(ct * 2 + 1) * 64 + lane], c);
    acc[ct] = c;
  }

  int r0 = nbase + wv * 16 + (lane >> 4) * 4;
  int cl = lane & 15;
#pragma unroll
  for (int ct = 0; ct < 4; ++ct)
#pragma unroll
    for (int r = 0; r < 4; ++r) {
      int node = r0 + r;
      if (node < NN) a_tab[(size_t)node * 64 + ct * 16 + cl] = acc[ct][r];
    }
#pragma unroll
  for (int ct = 4; ct < 8; ++ct)
#pragma unroll
    for (int r = 0; r < 4; ++r) {
      int node = r0 + r;
      if (node < NN) b_tab[(size_t)node * 64 + (ct - 4) * 16 + cl] = f2bf(acc[ct][r]);
    }
}

// ============================ MFMA node GEMMs ============================

__global__ __launch_bounds__(256) void transform_fused(const float* __restrict__ agg,
                                                       const float* __restrict__ W2,
                                                       const float* __restrict__ b2,
                                                       const int* __restrict__ cnt,
                                                       const float* __restrict__ W1,
                                                       float* __restrict__ a_tab,
                                                       ushort_t* __restrict__ b_tab) {
  __shared__ ushort_t w2l[8 * 64 * 8];
  __shared__ ushort_t w1l[16 * 64 * 8];
  __shared__ ushort_t xs[64 * 64];
  __shared__ ushort_t hs[64 * 64];
  int t = threadIdx.x;
  int nbase = blockIdx.x * 64;

  for (int i = t; i < 4096; i += 256) {
    int c = i & 63, k = i >> 6;
    float v = W2[k * 64 + c];
    int ct = c >> 4, lane = (c & 15) + ((k >> 3) & 3) * 16, kh = k >> 5;
    w2l[((ct * 2 + kh) * 64 + lane) * 8 + (k & 7)] = f2bf(v);
  }
  for (int i = t; i < 8192; i += 256) {
    int c = i & 127, k = i >> 7;
    float v = W1[((c >> 6) * 64 + k) * 64 + (c & 63)];
    int ct = c >> 4, lane = (c & 15) + ((k >> 3) & 3) * 16, kh = k >> 5;
    w1l[((ct * 2 + kh) * 64 + lane) * 8 + (k & 7)] = f2bf(v);
  }
  {
    const float4* f4 = (const float4*)agg;
    uint2* x2 = (uint2*)xs;
    for (int i = t; i < 1024; i += 256) {
      int ni = i >> 4, c4 = i & 15;
      int node = nbase + ni;
      float4 v = make_float4(0.f, 0.f, 0.f, 0.f);
      if (node < NN) v = f4[(size_t)nbase * 16 + i];
      uint2 pk;
      pk.x = bfpack2(v.x, v.y);
      pk.y = bfpack2(v.z, v.w);
      x2[(ni * 16 + c4) ^ ((ni & 7) << 1)] = pk;
    }
  }
  __syncthreads();

  int wv = t >> 6, lane = t & 63;
  int lrow = wv * 16 + (lane & 15);
  const bf16x8* xf = (const bf16x8*)xs;
  bf16x8 a0 = xf[(lrow * 8 + (lane >> 4)) ^ (lrow & 7)];
  bf16x8 a1 = xf[(lrow * 8 + 4 + (lane >> 4)) ^ (lrow & 7)];
  const bf16x8* w2f = (const bf16x8*)w2l;

  f32x4 hacc[4];
#pragma unroll
  for (int ct = 0; ct < 4; ++ct) {
    f32x4 c = {0.f, 0.f, 0.f, 0.f};
    c = mfma16(a0, w2f[(ct * 2 + 0) * 64 + lane], c);
    c = mfma16(a1, w2f[(ct * 2 + 1) * 64 + lane], c);
    hacc[ct] = c;
  }

  int r0 = nbase + wv * 16 + (lane >> 4) * 4;
  int lr0 = wv * 16 + (lane >> 4) * 4;
  int cl = lane & 15;
  float dcnt[4];
#pragma unroll
  for (int r = 0; r < 4; ++r) {
    int node = r0 + r;
    dcnt[r] = (node < NN) ? (float)(cnt[node] + 1) : 0.f;
  }
#pragma unroll
  for (int ct = 0; ct < 4; ++ct) {
    float bv = b2[ct * 16 + cl];
#pragma unroll
    for (int r = 0; r < 4; ++r) {
      float h = fmaxf(hacc[ct][r] + dcnt[r] * bv, 0.f);
      int lr = lr0 + r;
      hs[(lr * 64 + ct * 16 + cl) ^ ((lr & 7) << 3)] = f2bf(h);
    }
  }
  __syncthreads();

  const bf16x8* hf = (const bf16x8*)hs;
  bf16x8 h0 = hf[(lrow * 8 + (lane >> 4)) ^ (lrow & 7)];
  bf16x8 h1 = hf[(lrow * 8 + 4 + (lane >> 4)) ^ (lrow & 7)];
  const bf16x8* w1f = (const bf16x8*)w1l;

  f32x4 acc[8];
#pragma unroll
  for (int ct = 0; ct < 8; ++ct) {
    f32x4 c = {0.f, 0.f, 0.f, 0.f};
    c = mfma16(h0, w1f[(ct * 2 + 0) * 64 + lane], c);
    c = mfma16(h1, w1f[(ct * 2 + 1) * 64 + lane], c);
    acc[ct] = c;
  }
#pragma unroll
  for (int ct = 0; ct < 4; ++ct)
#pragma unroll
    for (int r = 0; r < 4; ++r) {
      int node = r0 + r;
      if (node < NN) a_tab[(size_t)node * 64 + ct * 16 + cl] = acc[ct][r];
    }
#pragma unroll
  for (int ct = 4; ct < 8; ++ct)
#pragma unroll
    for (int r = 0; r < 4; ++r) {
      int node = r0 + r;
      if (node < NN) b_tab[(size_t)node * 64 + (ct - 4) * 16 + cl] = f2bf(acc[ct][r]);
    }
}

__global__ __launch_bounds__(256) void transform_single(const float* __restrict__ agg,
                                                        const float* __restrict__ W2,
                                                        const float* __restrict__ b2,
                                                        const int* __restrict__ cnt,
                                                        float* __restrict__ out) {
  __shared__ ushort_t w2l[8 * 64 * 8];
  __shared__ ushort_t xs[64 * 64];
  int t = threadIdx.x;
  int nbase = blockIdx.x * 64;

  for (int i = t; i < 4096; i += 256) {
    int c = i & 63, k = i >> 6;
    float v = W2[k * 64 + c];
    int ct = c >> 4, lane = (c & 15) + ((k >> 3) & 3) * 16, kh = k >> 5;
    w2l[((ct * 2 + kh) * 64 + lane) * 8 + (k & 7)] = f2bf(v);
  }
  {
    const float4* f4 = (const float4*)agg;
    uint2* x2 = (uint2*)xs;
    for (int i = t; i < 1024; i += 256) {
      int ni = i >> 4, c4 = i & 15;
      int node = nbase + ni;
      float4 v = make_float4(0.f, 0.f, 0.f, 0.f);
      if (node < NN) v = f4[(size_t)nbase * 16 + i];
      uint2 pk;
      pk.x = bfpack2(v.x, v.y);
      pk.y = bfpack2(v.z, v.w);
      x2[(ni * 16 + c4) ^ ((ni & 7) << 1)] = pk;
    }
  }
  __syncthreads();

  int wv = t >> 6, lane = t & 63;
  int lrow = wv * 16 + (lane & 15);
  const bf16x8* xf = (const bf16x8*)xs;
  bf16x8 a0 = xf[(lrow * 8 + (lane >> 4)) ^ (lrow & 7)];
  bf16x8 a1 = xf[(lrow * 8 + 4 + (lane >> 4)) ^ (lrow & 7)];
  const bf16x8* w2f = (const bf16x8*)w2l;

  f32x4 acc[4];
#pragma unroll
  for (int ct = 0; ct < 4; ++ct) {
    f32x4 c = {0.f, 0.f, 0.f, 0.f};
    c = mfma16(a0, w2f[(ct * 2 + 0) * 64 + lane], c);
    c = mfma16(a1, w2f[(ct * 2 + 1) * 64 + lane], c);
    acc[ct] = c;
  }

  int r0 = nbase + wv * 16 + (lane >> 4) * 4;
  int cl = lane & 15;
  float dcnt[4];
#pragma unroll
  for (int r = 0; r < 4; ++r) {
    int node = r0 + r;
    dcnt[r] = (node < NN) ? (float)(cnt[node] + 1) : 0.f;
  }
#pragma unroll
  for (int ct = 0; ct < 4; ++ct) {
    float bv = b2[ct * 16 + cl];
#pragma unroll
    for (int r = 0; r < 4; ++r) {
      int node = r0 + r;
      if (node < NN)
        out[(size_t)node * 64 + ct * 16 + cl] = fmaxf(acc[ct][r] + dcnt[r] * bv, 0.f);
    }
  }
}

// ============================ edge aggregation ============================
// agg[n][c] = sum over in-edges+self of relu(a[n][c]+b1[c]+b_bf16[src][c])
// Fixed-stride buckets (CAP) + rare overflow list. Wave: 8 slots x 8 lanes.
__device__ __forceinline__ void acc_row(float4& acc0, float4& acc1, const float4& an0,
                                        const float4& an1, uint4 bv) {
  acc0.x += fmaxf(an0.x + __uint_as_float(bv.x << 16), 0.f);
  acc0.y += fmaxf(an0.y + __uint_as_float(bv.x & 0xFFFF0000u), 0.f);
  acc0.z += fmaxf(an0.z + __uint_as_float(bv.y << 16), 0.f);
  acc0.w += fmaxf(an0.w + __uint_as_float(bv.y & 0xFFFF0000u), 0.f);
  acc1.x += fmaxf(an1.x + __uint_as_float(bv.z << 16), 0.f);
  acc1.y += fmaxf(an1.y + __uint_as_float(bv.z & 0xFFFF0000u), 0.f);
  acc1.z += fmaxf(an1.z + __uint_as_float(bv.w << 16), 0.f);
  acc1.w += fmaxf(an1.w + __uint_as_float(bv.w & 0xFFFF0000u), 0.f);
}

__global__ __launch_bounds__(256) void edge_agg(const float* __restrict__ a_tab,
                                                const ushort_t* __restrict__ b_tab,
                                                const int* __restrict__ cnt,
                                                const int* __restrict__ srcs,
                                                const int* __restrict__ ov,
                                                const float* __restrict__ b1,
                                                float* __restrict__ agg) {
  int node = blockIdx.x * 4 + (threadIdx.x >> 6);
  if (node >= NN) return;
  int lane = threadIdx.x & 63;
  int slot = lane >> 3;
  int c8 = lane & 7;

  const float4* a4 = (const float4*)a_tab;
  const float4* b14 = (const float4*)b1;
  const uint4* bt = (const uint4*)b_tab;

  float4 an0 = add4(a4[(size_t)node * 16 + c8 * 2], b14[c8 * 2]);
  float4 an1 = add4(a4[(size_t)node * 16 + c8 * 2 + 1], b14[c8 * 2 + 1]);

  float4 acc0 = make_float4(0.f, 0.f, 0.f, 0.f);
  float4 acc1 = make_float4(0.f, 0.f, 0.f, 0.f);

  int deg = cnt[node];
  int m = (deg < CAP) ? deg : CAP;
  int base = node * CAP;

  if (slot == 0) {  // self loop
    uint4 bv = bt[(unsigned)(node * 8 + c8)];
    acc_row(acc0, acc1, an0, an1, bv);
    // overflow entries (essentially never populated; correctness fallback)
    int nov = cnt[NN];
    if (nov > OVCAP) nov = OVCAP;
    for (int i = 0; i < nov; ++i) {
      if (ov[2 * i] == node) {
        uint4 bo = bt[(unsigned)(ov[2 * i + 1] * 8 + c8)];
        acc_row(acc0, acc1, an0, an1, bo);
      }
    }
  }

  int e = slot;
  for (; e + 8 < m; e += 16) {  // two edges in flight
    int sA = srcs[base + e], sB = srcs[base + e + 8];
    uint4 bvA = bt[(unsigned)(sA * 8 + c8)];
    uint4 bvB = bt[(unsigned)(sB * 8 + c8)];
    acc_row(acc0, acc1, an0, an1, bvA);
    acc_row(acc0, acc1, an0, an1, bvB);
  }
  for (; e < m; e += 8) {
    int s = srcs[base + e];
    uint4 bv = bt[(unsigned)(s * 8 + c8)];
    acc_row(acc0, acc1, an0, an1, bv);
  }

#pragma unroll
  for (int mm = 8; mm <= 32; mm <<= 1) {
    acc0.x += __shfl_xor(acc0.x, mm, 64);
    acc0.y += __shfl_xor(acc0.y, mm, 64);
    acc0.z += __shfl_xor(acc0.z, mm, 64);
    acc0.w += __shfl_xor(acc0.w, mm, 64);
    acc1.x += __shfl_xor(acc1.x, mm, 64);
    acc1.y += __shfl_xor(acc1.y, mm, 64);
    acc1.z += __shfl_xor(acc1.z, mm, 64);
    acc1.w += __shfl_xor(acc1.w, mm, 64);
  }
  if (slot == 0) {
    float4* agg4 = (float4*)agg;
    agg4[(size_t)node * 16 + c8 * 2] = acc0;
    agg4[(size_t)node * 16 + c8 * 2 + 1] = acc1;
  }
}

// ============================ pooling + head ============================

__global__ __launch_bounds__(256) void pool_partial(const float* __restrict__ h,
                                                    const int* __restrict__ gstart,
                                                    float* __restrict__ partials) {
  int g = blockIdx.x >> 3, q = blockIdx.x & 7;
  int lane = threadIdx.x & 63, w = threadIdx.x >> 6;
  int s = gstart[g], e = gstart[g + 1];
  int len = e - s;
  int qs = s + (len * q) / 8, qe = s + (len * (q + 1)) / 8;
  float a0 = 0.f, a1 = 0.f;
  int n = qs + w;
  for (; n + 4 < qe; n += 8) {
    a0 += h[(size_t)n * 64 + lane];
    a1 += h[(size_t)(n + 4) * 64 + lane];
  }
  for (; n < qe; n += 4) a0 += h[(size_t)n * 64 + lane];
  __shared__ float red[4][64];
  red[w][lane] = a0 + a1;
  __syncthreads();
  if (w == 0)
    partials[(size_t)(g * 8 + q) * 64 + lane] =
        red[0][lane] + red[1][lane] + red[2][lane] + red[3][lane];
}

__global__ void final_kernel(const float* __restrict__ partials, const int* __restrict__ gstart,
                             const float* __restrict__ Wl, const float* __restrict__ bl,
                             float* __restrict__ out) {
  int g = blockIdx.x;
  int t = threadIdx.x;  // 64
  __shared__ float pm[64];
  float inv = 1.f / fmaxf((float)(gstart[g + 1] - gstart[g]), 1.f);
  float s = 0.f;
#pragma unroll
  for (int q = 0; q < 8; ++q) s += partials[(size_t)(g * 8 + q) * 64 + t];
  pm[t] = s * inv;
  __syncthreads();
  float acc = bl[t];
  for (int k = 0; k < 64; ++k) acc += pm[k] * Wl[k * 64 + t];
  out[g * 64 + t] = acc;
}

// ============================ launch ============================

extern "C" void kernel_launch(void* const* d_in, const int* in_sizes, int n_in,
                              void* d_out, int out_size, void* d_ws, size_t ws_size,
                              hipStream_t stream) {
  const float* x = (const float*)d_in[0];
  const int* ei = (const int*)d_in[1];
  const int* batch = (const int*)d_in[2];
  const float* W1a = (const float*)d_in[3];
  const float* b1a = (const float*)d_in[4];
  const float* W2a = (const float*)d_in[5];
  const float* b2a = (const float*)d_in[6];
  const float* W1b = (const float*)d_in[7];
  const float* b1b = (const float*)d_in[8];
  const float* W2b = (const float*)d_in[9];
  const float* b2b = (const float*)d_in[10];
  const float* Wl = (const float*)d_in[11];
  const float* bl = (const float*)d_in[12];
  float* out = (float*)d_out;

  char* p = (char*)d_ws;
  auto alloc = [&](size_t bytes) {
    char* r = p;
    p += (bytes + 255) & ~(size_t)255;
    return r;
  };
  int* cnt = (int*)alloc((NN + 1) * sizeof(int));  // cnt[NN] = overflow counter
  int* gstart = (int*)alloc((NG + 1) * sizeof(int));
  int* srcs = (int*)alloc((size_t)NN * CAP * sizeof(int));
  int* ov = (int*)alloc((size_t)OVCAP * 2 * sizeof(int));
  float* a_tab = (float*)alloc((size_t)NN * 64 * sizeof(float));
  ushort_t* b_tab = (ushort_t*)alloc((size_t)NN * 64 * sizeof(ushort_t));
  float* hbuf = (float*)alloc((size_t)NN * 64 * sizeof(float));
  float* partials = (float*)alloc((size_t)NG * 8 * 64 * sizeof(float));

  int tb = (NN + 63) / 64;  // 782
  int eb = (NN + 3) / 4;    // 12500

  setup_kernel<<<(NN + 256) / 256, 256, 0, stream>>>(batch, cnt, gstart);
  // fused: bucket scatter (blocks 0..1023) + layer-1 dual transform (blocks 1024..)
  scatter_dual<<<1024 + tb, 256, 0, stream>>>(ei, cnt, srcs, ov, x, W1a, a_tab, b_tab);
  edge_agg<<<eb, 256, 0, stream>>>(a_tab, b_tab, cnt, srcs, ov, b1a, hbuf);
  transform_fused<<<tb, 256, 0, stream>>>(hbuf, W2a, b2a, cnt, W1b, a_tab, b_tab);
  edge_agg<<<eb, 256, 0, stream>>>(a_tab, b_tab, cnt, srcs, ov, b1b, hbuf);
  transform_single<<<tb, 256, 0, stream>>>(hbuf, W2b, b2b, cnt, hbuf);
  pool_partial<<<NG * 8, 256, 0, stream>>>(hbuf, gstart, partials);
  final_kernel<<<NG, 64, 0, stream>>>(partials, gstart, Wl, bl, out);
}